// Round 12
// baseline (357.048 us; speedup 1.0000x reference)
//
#include <hip/hip_runtime.h>

#define NN 16384          // nodes
#define NE 262144         // edges
#define N64 (NN * 64)

typedef unsigned short u16;
typedef __attribute__((ext_vector_type(8))) short short8;
typedef __attribute__((ext_vector_type(4))) float f32x4;

__device__ __forceinline__ float us2f(u16 u) {
    union { unsigned int i; float f; } v; v.i = ((unsigned int)u) << 16; return v.f;
}
__device__ __forceinline__ u16 f2us(float x) {   // f32 -> bf16 bits, RNE
    union { float f; unsigned int i; } u; u.f = x;
    unsigned int r = u.i + 0x7FFF + ((u.i >> 16) & 1);
    return (u16)(r >> 16);
}
__device__ __forceinline__ float silu_f(float x) { return x / (1.0f + __expf(-x)); }
__device__ __forceinline__ float ldf(const void* p, long i, int f) {
    return f ? ((const float*)p)[i] : us2f(((const u16*)p)[i]);
}

// ---------------- dtype sniff (drives only k_convert) --------------------------
__global__ void k_sniff(const u16* __restrict__ re, int* __restrict__ flag) {
    int t = threadIdx.x;
    int hit = (re[t] >= 0x4000) ? 1 : 0;
    unsigned long long b = __ballot(hit);
    if (t == 0) *flag = (__popcll(b) >= 4) ? 1 : 0;   // 1 => f32 inputs
}

// ---------------- convert all float tensors to bf16 + transposes + hist --------
#define SB0 1048576L
#define SB1 4194304L
#define SB2 4456448L
#define SB3 5242880L
#define SB4 7340032L
#define SB5 7344128L
#define SB6 7348224L
#define SB7 7348736L
#define SB8 7365120L
#define SB9 7381504L
#define SB10 7389696L
#define SB11 7422464L
#define SB12 7438848L   // total; /256 = 29058 blocks

__global__ void k_convert(const void* x0, const void* x1, const void* ey0, const void* ey1,
                          const void* re, const void* Wup0, const void* Wup1, const void* Rw1,
                          const void* Rw2, const void* Wd0, const void* Wd1, const void* Wsc0,
                          const void* Wsc1, const int* __restrict__ flag,
                          const int* __restrict__ recv, int* __restrict__ cnt,
                          u16* c_x0, u16* x1T, u16* c_ey0, u16* c_ey1, u16* c_re,
                          u16* c_Wup0, u16* c_Wup1, u16* c_Rw1, u16* c_Rw2,
                          u16* c_Wd0T, u16* c_Wd1T, u16* c_Wsc0T, u16* c_Wsc1T) {
    long i = (long)blockIdx.x * 256 + threadIdx.x;
    int f = *flag;
    if (i < NE) atomicAdd(&cnt[recv[i]], 1);          // fused histogram
    if (i < SB0)       { c_x0[i]          = f2us(ldf(x0, i, f)); }
    else if (i < SB1)  {
        long j = i - SB0;
        int n = (int)(j / 192); int r = (int)(j % 192); int m = r / 3; int c = r % 3;
        x1T[(long)c * N64 + (long)n * 64 + m] = f2us(ldf(x1, j, f));
    }
    else if (i < SB2)  { c_ey0[i - SB1]   = f2us(ldf(ey0, i - SB1, f)); }
    else if (i < SB3)  { c_ey1[i - SB2]   = f2us(ldf(ey1, i - SB2, f)); }
    else if (i < SB4)  { c_re[i - SB3]    = f2us(ldf(re, i - SB3, f)); }
    else if (i < SB5)  { c_Wup0[i - SB4]  = f2us(ldf(Wup0, i - SB4, f)); }
    else if (i < SB6)  { c_Wup1[i - SB5]  = f2us(ldf(Wup1, i - SB5, f)); }
    else if (i < SB7)  { c_Rw1[i - SB6]   = f2us(ldf(Rw1, i - SB6, f)); }
    else if (i < SB8)  { c_Rw2[i - SB7]   = f2us(ldf(Rw2, i - SB7, f)); }
    else if (i < SB9)  {            // Wd0 [128k][128n] -> T [128n][128k]
        long j = i - SB8; int k = (int)(j >> 7), n = (int)(j & 127);
        c_Wd0T[(long)n * 128 + k] = f2us(ldf(Wd0, j, f));
    }
    else if (i < SB10) {            // Wd1 [128k][64n] -> T [64n][128k]
        long j = i - SB9; int k = (int)(j >> 6), n = (int)(j & 63);
        c_Wd1T[(long)n * 128 + k] = f2us(ldf(Wd1, j, f));
    }
    else if (i < SB11) {            // Wsc0 [4][64k][128n] -> T [4][128n][64k]
        long j = i - SB10; int s = (int)(j >> 13); int r = (int)(j & 8191);
        int k = r >> 7, n = r & 127;
        c_Wsc0T[(long)s * 8192 + (long)n * 64 + k] = f2us(ldf(Wsc0, j, f));
    }
    else {                          // Wsc1 [4][64k][64n] -> T [4][64n][64k]
        long j = i - SB11; int s = (int)(j >> 12); int r = (int)(j & 4095);
        int k = r >> 6, n = r & 63;
        c_Wsc1T[(long)s * 4096 + (long)n * 64 + k] = f2us(ldf(Wsc1, j, f));
    }
}

// ---------------- CSR scan + scatter -------------------------------------------
__global__ void k_scan(const int* __restrict__ cnt, int* __restrict__ offs,
                       int* __restrict__ cursor) {
    __shared__ int sd[256];
    int t = threadIdx.x;
    int base = t * 64;
    const int4* c4 = (const int4*)cnt;
    int loc[64];
#pragma unroll
    for (int i = 0; i < 16; i++) {
        int4 v = c4[t * 16 + i];
        loc[i * 4 + 0] = v.x; loc[i * 4 + 1] = v.y; loc[i * 4 + 2] = v.z; loc[i * 4 + 3] = v.w;
    }
    int sum = 0;
#pragma unroll
    for (int i = 0; i < 64; i++) sum += loc[i];
    sd[t] = sum; __syncthreads();
    for (int off = 1; off < 256; off <<= 1) {
        int v = (t >= off) ? sd[t - off] : 0;
        __syncthreads();
        sd[t] += v;
        __syncthreads();
    }
    int run = sd[t] - sum;
    for (int i = 0; i < 64; i++) {
        offs[base + i] = run; cursor[base + i] = run;
        run += loc[i];
    }
    if (t == 255) offs[NN] = run;
}

__global__ void k_scatter(const int* __restrict__ recv, const int* __restrict__ senders,
                          const u16* __restrict__ ey0, const u16* __restrict__ ey1,
                          int* __restrict__ cursor,
                          int* __restrict__ cpos, int4* __restrict__ meta) {
    int e = blockIdx.x * 256 + threadIdx.x;
    int p = atomicAdd(&cursor[recv[e]], 1);
    cpos[e] = p;
    unsigned y0  = ey0[e];
    unsigned y1x = ey1[(long)e * 3 + 0];
    unsigned y1y = ey1[(long)e * 3 + 1];
    unsigned y1z = ey1[(long)e * 3 + 2];
    int4 m;
    m.x = senders[e];
    m.y = (int)(y0 | (y1x << 16));
    m.z = (int)(y1y | (y1z << 16));
    m.w = e;
    meta[p] = m;
}

// ---------------- linear_up: h[node][64ch][4comp] interleaved bf16 --------------
__global__ void k_up_gemm(const u16* __restrict__ x0, const u16* __restrict__ x1T,
                          const u16* __restrict__ Wup0, const u16* __restrict__ Wup1,
                          u16* __restrict__ h) {
    int inst = blockIdx.y;
    int wv = threadIdx.x >> 6, lane = threadIdx.x & 63;
    int lhi = lane >> 4, llo = lane & 15;
    int mb = blockIdx.x * 256 + wv * 64;
    const u16* B = (inst == 0) ? Wup0 : Wup1;
    const u16* A = (inst == 0) ? x0 : (x1T + (long)(inst - 1) * N64);

    short8 bfr[4][2];
#pragma unroll
    for (int t = 0; t < 4; t++)
#pragma unroll
        for (int s = 0; s < 2; s++)
#pragma unroll
            for (int j = 0; j < 8; j++)
                bfr[t][s][j] = (short)B[(long)(s * 32 + lhi * 8 + j) * 64 + t * 16 + llo];

    f32x4 acc[4][4];
#pragma unroll
    for (int i = 0; i < 4; i++)
#pragma unroll
        for (int t = 0; t < 4; t++) acc[i][t] = 0.0f;

#pragma unroll
    for (int s = 0; s < 2; s++) {
        short8 af[4];
#pragma unroll
        for (int i = 0; i < 4; i++)
            af[i] = *reinterpret_cast<const short8*>(A + (long)(mb + i * 16 + llo) * 64 + s * 32 + lhi * 8);
#pragma unroll
        for (int i = 0; i < 4; i++)
#pragma unroll
            for (int t = 0; t < 4; t++)
                acc[i][t] = __builtin_amdgcn_mfma_f32_16x16x32_bf16(af[i], bfr[t][s], acc[i][t], 0, 0, 0);
    }
#pragma unroll
    for (int i = 0; i < 4; i++)
#pragma unroll
        for (int t = 0; t < 4; t++)
#pragma unroll
            for (int r = 0; r < 4; r++)
                h[(long)(mb + i * 16 + lhi * 4 + r) * 256 + (t * 16 + llo) * 4 + inst] =
                    f2us(acc[i][t][r] * 0.125f);
}

// ---------------- radial MLP: dense edge order, scatter full CSR records --------
#define RROW 272
__global__ void k_radialE(const u16* __restrict__ re, const u16* __restrict__ Rw1,
                          const u16* __restrict__ Rw2, const int* __restrict__ cpos,
                          const int* __restrict__ offs,
                          u16* __restrict__ wkc, int n0, int n1, int cap) {
    __shared__ u16 hid_s[64][72];
    __shared__ u16 w_lds[64 * RROW];
    int tid = threadIdx.x;
    int wv = tid >> 6, lane = tid & 63, lhi = lane >> 4, llo = lane & 15;
    int e0 = blockIdx.x * 64;
    int p0 = offs[n0];
    int p1 = offs[n1];
    if (p1 > p0 + cap) p1 = p0 + cap;

    {
        int el = tid >> 2;
        int jb = (tid & 3) * 16;
        int e = e0 + el;
        short8 r8 = *reinterpret_cast<const short8*>(re + (long)e * 8);
        float rr[8];
#pragma unroll
        for (int r = 0; r < 8; r++) rr[r] = us2f((u16)r8[r]);
        float hv[16];
#pragma unroll
        for (int q = 0; q < 2; q++) {
            short8 w8 = *reinterpret_cast<const short8*>(Rw1 + jb + q * 8);
#pragma unroll
            for (int j = 0; j < 8; j++) hv[q * 8 + j] = rr[0] * us2f((u16)w8[j]);
        }
#pragma unroll
        for (int r = 1; r < 8; r++) {
#pragma unroll
            for (int q = 0; q < 2; q++) {
                short8 w8 = *reinterpret_cast<const short8*>(Rw1 + (long)r * 64 + jb + q * 8);
#pragma unroll
                for (int j = 0; j < 8; j++) hv[q * 8 + j] += rr[r] * us2f((u16)w8[j]);
            }
        }
#pragma unroll
        for (int q = 0; q < 4; q++) {
            ushort4 pk;
            pk.x = f2us(silu_f(hv[q * 4 + 0] * 0.35355339059327373f));
            pk.y = f2us(silu_f(hv[q * 4 + 1] * 0.35355339059327373f));
            pk.z = f2us(silu_f(hv[q * 4 + 2] * 0.35355339059327373f));
            pk.w = f2us(silu_f(hv[q * 4 + 3] * 0.35355339059327373f));
            *reinterpret_cast<ushort4*>(&hid_s[el][jb + q * 4]) = pk;
        }
    }
    __syncthreads();
    {
        short8 bfr[4][2];
#pragma unroll
        for (int t = 0; t < 4; t++)
#pragma unroll
            for (int s = 0; s < 2; s++)
#pragma unroll
                for (int j = 0; j < 8; j++)
                    bfr[t][s][j] = (short)Rw2[(long)(s * 32 + lhi * 8 + j) * 256 + wv * 64 + t * 16 + llo];
        f32x4 acc[4][4];
#pragma unroll
        for (int i = 0; i < 4; i++)
#pragma unroll
            for (int t = 0; t < 4; t++) acc[i][t] = 0.0f;
#pragma unroll
        for (int s = 0; s < 2; s++) {
            short8 af[4];
#pragma unroll
            for (int i = 0; i < 4; i++)
                af[i] = *reinterpret_cast<const short8*>(&hid_s[i * 16 + llo][s * 32 + lhi * 8]);
#pragma unroll
            for (int i = 0; i < 4; i++)
#pragma unroll
                for (int t = 0; t < 4; t++)
                    acc[i][t] = __builtin_amdgcn_mfma_f32_16x16x32_bf16(af[i], bfr[t][s], acc[i][t], 0, 0, 0);
        }
#pragma unroll
        for (int i = 0; i < 4; i++)
#pragma unroll
            for (int t = 0; t < 4; t++)
#pragma unroll
                for (int r = 0; r < 4; r++)
                    w_lds[(i * 16 + lhi * 4 + r) * RROW + wv * 64 + t * 16 + llo] =
                        f2us(acc[i][t][r] * 0.125f);
    }
    __syncthreads();
    {
        int i = tid >> 2, q = tid & 3;
        int cp = cpos[e0 + i];
        if (cp >= p0 && cp < p1) {
            const u16* src = &w_lds[i * RROW + q * 64];
            u16* dst = wkc + (long)(cp - p0) * 256 + q * 64;
#pragma unroll
            for (int j = 0; j < 8; j++)
                *reinterpret_cast<f32x4*>(dst + j * 8) = *reinterpret_cast<const f32x4*>(src + j * 8);
        }
    }
}

// ---------------- gather only: per-node message accumulation -> abuf bf16 -------
__global__ void k_gather(const int* __restrict__ offs, const u16* __restrict__ wkc,
                         const int4* __restrict__ meta, const u16* __restrict__ h,
                         u16* __restrict__ abuf, int n0, int cap) {
    int wv = threadIdx.x >> 6, l = threadIdx.x & 63;
    int node = n0 + blockIdx.x * 4 + wv;
    int cbase = offs[n0];
    int beg = offs[node] - cbase, end = offs[node + 1] - cbase;
    if (beg > cap) beg = cap;
    if (end > cap) end = cap;

    float A0a = 0.f, A0b = 0.f;
    float Ax = 0.f, Ay = 0.f, Az = 0.f;
    float Bx = 0.f, By = 0.f, Bz = 0.f;

    int idx = beg;
    for (; idx + 2 <= end; idx += 2) {
        int4 m0 = meta[cbase + idx];
        int4 m1 = meta[cbase + idx + 1];
        const u16* wr0 = wkc + (long)idx * 256;
        const u16* wr1 = wkc + (long)(idx + 1) * 256;
        float w00 = us2f(wr0[l]),       w01 = us2f(wr0[64 + l]);
        float w02 = us2f(wr0[128 + l]), w03 = us2f(wr0[192 + l]);
        float w10 = us2f(wr1[l]),       w11 = us2f(wr1[64 + l]);
        float w12 = us2f(wr1[128 + l]), w13 = us2f(wr1[192 + l]);
        ushort4 h0v = *reinterpret_cast<const ushort4*>(h + (long)m0.x * 256 + l * 4);
        ushort4 h1v = *reinterpret_cast<const ushort4*>(h + (long)m1.x * 256 + l * 4);
        {
            float y0  = us2f((u16)((unsigned)m0.y & 0xffff));
            float y1x = us2f((u16)((unsigned)m0.y >> 16));
            float y1y = us2f((u16)((unsigned)m0.z & 0xffff));
            float y1z = us2f((u16)((unsigned)m0.z >> 16));
            float s0 = us2f(h0v.x), s1x = us2f(h0v.y), s1y = us2f(h0v.z), s1z = us2f(h0v.w);
            A0a += w00 * s0 * y0;
            A0b += w01 * (s1x * y1x + s1y * y1y + s1z * y1z);
            Ax += w02 * s0 * y1x; Ay += w02 * s0 * y1y; Az += w02 * s0 * y1z;
            Bx += w03 * s1x * y0; By += w03 * s1y * y0; Bz += w03 * s1z * y0;
        }
        {
            float y0  = us2f((u16)((unsigned)m1.y & 0xffff));
            float y1x = us2f((u16)((unsigned)m1.y >> 16));
            float y1y = us2f((u16)((unsigned)m1.z & 0xffff));
            float y1z = us2f((u16)((unsigned)m1.z >> 16));
            float s0 = us2f(h1v.x), s1x = us2f(h1v.y), s1y = us2f(h1v.z), s1z = us2f(h1v.w);
            A0a += w10 * s0 * y0;
            A0b += w11 * (s1x * y1x + s1y * y1y + s1z * y1z);
            Ax += w12 * s0 * y1x; Ay += w12 * s0 * y1y; Az += w12 * s0 * y1z;
            Bx += w13 * s1x * y0; By += w13 * s1y * y0; Bz += w13 * s1z * y0;
        }
    }
    if (idx < end) {
        int4 m0 = meta[cbase + idx];
        const u16* wr0 = wkc + (long)idx * 256;
        float w00 = us2f(wr0[l]),       w01 = us2f(wr0[64 + l]);
        float w02 = us2f(wr0[128 + l]), w03 = us2f(wr0[192 + l]);
        ushort4 h0v = *reinterpret_cast<const ushort4*>(h + (long)m0.x * 256 + l * 4);
        float y0  = us2f((u16)((unsigned)m0.y & 0xffff));
        float y1x = us2f((u16)((unsigned)m0.y >> 16));
        float y1y = us2f((u16)((unsigned)m0.z & 0xffff));
        float y1z = us2f((u16)((unsigned)m0.z >> 16));
        float s0 = us2f(h0v.x), s1x = us2f(h0v.y), s1y = us2f(h0v.z), s1z = us2f(h0v.w);
        A0a += w00 * s0 * y0;
        A0b += w01 * (s1x * y1x + s1y * y1y + s1z * y1z);
        Ax += w02 * s0 * y1x; Ay += w02 * s0 * y1y; Az += w02 * s0 * y1z;
        Bx += w03 * s1x * y0; By += w03 * s1y * y0; Bz += w03 * s1z * y0;
    }

    const float qn = 0.25f;                 // 1/sqrt(avg_neigh)
    const float rs3 = 0.57735026918962576f; // 1/sqrt(3)
    u16* ab = abuf + (long)node * 512;      // [a0(128) | a1x(128) | a1y | a1z]
    ab[l]        = f2us(A0a * qn);
    ab[64 + l]   = f2us(A0b * qn * rs3);
    ab[128 + l]  = f2us(Ax * qn);  ab[192 + l] = f2us(Bx * qn);
    ab[256 + l]  = f2us(Ay * qn);  ab[320 + l] = f2us(By * qn);
    ab[384 + l]  = f2us(Az * qn);  ab[448 + l] = f2us(Bz * qn);
}

// ---------------- linear_down + species sc + gate (MFMA, transposed weights) ----
// Block = 64 nodes, 5 waves (g = {scal, gate, vx, vy, vz}). Two phases of 32
// nodes: compute -> LDS -> coalesced gated flush of the [node][64][3] region.
__global__ void k_down(const u16* __restrict__ abuf, const u16* __restrict__ x0,
                       const u16* __restrict__ x1T, const int* __restrict__ species,
                       const u16* __restrict__ Wd0T, const u16* __restrict__ Wd1T,
                       const u16* __restrict__ Wsc0T, const u16* __restrict__ Wsc1T,
                       float* __restrict__ out) {
    __shared__ float gate_s[32][65];    // 8.3 KB
    __shared__ float vec_s[32][196];    // 24.5 KB (192 used, 196 stride)
    __shared__ int sp_s[64];
    int tid = threadIdx.x;
    int g = tid >> 6;
    int lane = tid & 63, lhi = lane >> 4, llo = lane & 15;
    int node0 = blockIdx.x * 64;
    if (tid < 64) sp_s[tid] = species[node0 + tid];
    __syncthreads();

    const u16 *Ad, *BdT, *As, *BsT; int bcol, sstr;
    if (g <= 1) { Ad = abuf; BdT = Wd0T; bcol = g * 64; As = x0; BsT = Wsc0T; sstr = 8192; }
    else { Ad = abuf + (g - 1) * 128; BdT = Wd1T; bcol = 0;
           As = x1T + (long)(g - 2) * N64; BsT = Wsc1T; sstr = 4096; }

    short8 bd[4][4];   // [coltile][kstep] — one 16B load each (transposed weights)
#pragma unroll
    for (int ct = 0; ct < 4; ct++)
#pragma unroll
        for (int ks = 0; ks < 4; ks++)
            bd[ct][ks] = *reinterpret_cast<const short8*>(
                BdT + (long)(bcol + ct * 16 + llo) * 128 + ks * 32 + lhi * 8);

    const float inv2 = 0.08838834764831845f;  // 1/sqrt(128)
    const float inv  = 0.125f;                // 1/sqrt(64)

    for (int phase = 0; phase < 2; phase++) {
#pragma unroll
        for (int rr = 0; rr < 2; rr++) {
            int rt = phase * 2 + rr;
            int arow = node0 + rt * 16 + llo;
            f32x4 accd[4];
#pragma unroll
            for (int ct = 0; ct < 4; ct++) accd[ct] = 0.0f;
#pragma unroll
            for (int ks = 0; ks < 4; ks++) {
                short8 a = *reinterpret_cast<const short8*>(Ad + (long)arow * 512 + ks * 32 + lhi * 8);
#pragma unroll
                for (int ct = 0; ct < 4; ct++)
                    accd[ct] = __builtin_amdgcn_mfma_f32_16x16x32_bf16(a, bd[ct][ks], accd[ct], 0, 0, 0);
            }
            int spv[4];
#pragma unroll
            for (int r = 0; r < 4; r++) spv[r] = sp_s[rt * 16 + lhi * 4 + r];
            f32x4 res[4];
#pragma unroll
            for (int ct = 0; ct < 4; ct++) res[ct] = 0.0f;
            for (int s = 0; s < 4; s++) {
                short8 bs[4][2];
#pragma unroll
                for (int ct = 0; ct < 4; ct++)
#pragma unroll
                    for (int ks = 0; ks < 2; ks++)
                        bs[ct][ks] = *reinterpret_cast<const short8*>(
                            BsT + (long)s * sstr + (long)(bcol + ct * 16 + llo) * 64 + ks * 32 + lhi * 8);
                f32x4 accs[4];
#pragma unroll
                for (int ct = 0; ct < 4; ct++) accs[ct] = 0.0f;
#pragma unroll
                for (int ks = 0; ks < 2; ks++) {
                    short8 a2 = *reinterpret_cast<const short8*>(As + (long)arow * 64 + ks * 32 + lhi * 8);
#pragma unroll
                    for (int ct = 0; ct < 4; ct++)
                        accs[ct] = __builtin_amdgcn_mfma_f32_16x16x32_bf16(a2, bs[ct][ks], accs[ct], 0, 0, 0);
                }
#pragma unroll
                for (int ct = 0; ct < 4; ct++)
#pragma unroll
                    for (int r = 0; r < 4; r++)
                        if (spv[r] == s) res[ct][r] = accs[ct][r];
            }
#pragma unroll
            for (int ct = 0; ct < 4; ct++)
#pragma unroll
                for (int r = 0; r < 4; r++) {
                    float fv = 0.5f * (accd[ct][r] * inv2 + res[ct][r] * inv);
                    int row = rt * 16 + lhi * 4 + r;
                    int prow = row - phase * 32;
                    int col = ct * 16 + llo;
                    if (g == 0) out[(long)(node0 + row) * 64 + col] = silu_f(fv);
                    else if (g == 1) gate_s[prow][col] = silu_f(fv);
                    else vec_s[prow][col * 3 + (g - 2)] = fv;
                }
        }
        __syncthreads();
        // gated, fully-coalesced flush of this phase's 32 nodes (32*192 floats)
        for (int p = tid; p < 1536; p += 320) {
            int nd = p / 48, rem = p % 48;
            f32x4 v = *reinterpret_cast<const f32x4*>(&vec_s[nd][rem * 4]);
#pragma unroll
            for (int i = 0; i < 4; i++) {
                int fi = rem * 4 + i;
                v[i] *= gate_s[nd][fi / 3];
            }
            long dst = (long)N64 + (long)(node0 + phase * 32 + nd) * 192 + rem * 4;
            *reinterpret_cast<f32x4*>(out + dst) = v;
        }
        __syncthreads();
    }
}

// ---------------- host launch --------------------------------------------------
extern "C" void kernel_launch(void* const* d_in, const int* in_sizes, int n_in,
                              void* d_out, int out_size, void* d_ws, size_t ws_size,
                              hipStream_t stream) {
    const int* senders   = (const int*)d_in[5];
    const int* receivers = (const int*)d_in[6];
    const int* species   = (const int*)d_in[7];
    float* out = (float*)d_out;

    char* ws = (char*)d_ws;
    size_t o = 0;
    auto alloc = [&](size_t bytes) { size_t p = o; o = (o + bytes + 255) & ~255UL; return p; };
    int* flag   = (int*)(ws + alloc(4));
    int* cnt    = (int*)(ws + alloc((size_t)NN * 4));
    int* offs   = (int*)(ws + alloc((size_t)(NN + 1) * 4));
    int* cursor = (int*)(ws + alloc((size_t)NN * 4));
    int* cpos   = (int*)(ws + alloc((size_t)NE * 4));
    int4* meta  = (int4*)(ws + alloc((size_t)NE * 16));
    u16* c_x0   = (u16*)(ws + alloc(SB0 * 2));
    u16* x1T    = (u16*)(ws + alloc((size_t)3 * N64 * 2));
    u16* c_ey0  = (u16*)(ws + alloc((SB2 - SB1) * 2));
    u16* c_ey1  = (u16*)(ws + alloc((SB3 - SB2) * 2));
    u16* c_re   = (u16*)(ws + alloc((SB4 - SB3) * 2));
    u16* c_Wup0 = (u16*)(ws + alloc((SB5 - SB4) * 2));
    u16* c_Wup1 = (u16*)(ws + alloc((SB6 - SB5) * 2));
    u16* c_Rw1  = (u16*)(ws + alloc((SB7 - SB6) * 2));
    u16* c_Rw2  = (u16*)(ws + alloc((SB8 - SB7) * 2));
    u16* c_Wd0T = (u16*)(ws + alloc((SB9 - SB8) * 2));
    u16* c_Wd1T = (u16*)(ws + alloc((SB10 - SB9) * 2));
    u16* c_Wsc0T= (u16*)(ws + alloc((SB11 - SB10) * 2));
    u16* c_Wsc1T= (u16*)(ws + alloc((SB12 - SB11) * 2));
    u16* h      = (u16*)(ws + alloc((size_t)NN * 256 * 2));   // [node][64][4]
    u16* abuf   = (u16*)(ws + alloc((size_t)NN * 512 * 2));   // [node][512]
    size_t fixed = o;                       // ~45 MB
    int C = 128;
    for (int c = 1; c <= 128; c <<= 1) {
        size_t cap = (size_t)NE / c + 2048;
        if (fixed + cap * 512 <= ws_size) { C = c; break; }
    }
    int CAP = NE / C + 2048;
    u16* wk = (u16*)(ws + alloc((size_t)CAP * 512));
    int NNC = NN / C;

    k_sniff<<<1, 64, 0, stream>>>((const u16*)d_in[4], flag);
    (void)hipMemsetAsync(cnt, 0, (size_t)NN * 4, stream);
    k_convert<<<29058, 256, 0, stream>>>(d_in[0], d_in[1], d_in[2], d_in[3], d_in[4],
        d_in[8], d_in[9], d_in[10], d_in[11], d_in[12], d_in[13], d_in[14], d_in[15],
        flag, receivers, cnt,
        c_x0, x1T, c_ey0, c_ey1, c_re,
        c_Wup0, c_Wup1, c_Rw1, c_Rw2, c_Wd0T, c_Wd1T, c_Wsc0T, c_Wsc1T);
    k_scan<<<1, 256, 0, stream>>>(cnt, offs, cursor);
    k_scatter<<<NE / 256, 256, 0, stream>>>(receivers, senders, c_ey0, c_ey1,
                                            cursor, cpos, meta);

    k_up_gemm<<<dim3(NN / 256, 4), 256, 0, stream>>>(c_x0, x1T, c_Wup0, c_Wup1, h);

    for (int c = 0; c < C; c++) {
        int n0 = c * NNC, n1 = n0 + NNC;
        k_radialE<<<NE / 64, 256, 0, stream>>>(c_re, c_Rw1, c_Rw2, cpos, offs,
                                               wk, n0, n1, CAP);
        k_gather<<<NNC / 4, 256, 0, stream>>>(offs, wk, meta, h, abuf, n0, CAP);
    }

    k_down<<<NN / 64, 320, 0, stream>>>((const u16*)abuf, c_x0, x1T, species,
                                        c_Wd0T, c_Wd1T, c_Wsc0T, c_Wsc1T, out);
}